// Round 20
// baseline (576.114 us; speedup 1.0000x reference)
//
#include <hip/hip_runtime.h>
#include <hip/hip_bf16.h>

#define GAS __attribute__((address_space(1)))
#define LAS __attribute__((address_space(3)))

typedef __attribute__((ext_vector_type(8))) short   bf16x8;
typedef __attribute__((ext_vector_type(4))) float   f32x4;
typedef __attribute__((ext_vector_type(16))) float  f32x16;
typedef __attribute__((ext_vector_type(4))) float   f4;
typedef __attribute__((ext_vector_type(8))) short   s8v;
typedef __attribute__((ext_vector_type(4))) unsigned int u32x4;

#define NB  64
#define NS  512
#define ND  768
#define NH  12
#define NHS 64
#define NM  (NB*NS)    /* 32768 */

// 0.125 * log2(e): folded into Q so softmax uses exp2 directly
#define QSCALE 0.18033688011112042f

__device__ __forceinline__ unsigned short f2bf(float x){
  unsigned int u = __float_as_uint(x);
  u += 0x7fffu + ((u >> 16) & 1u);       // round-to-nearest-even
  return (unsigned short)(u >> 16);
}

__device__ __forceinline__ f32x4 mfma16(bf16x8 a, bf16x8 b, f32x4 c){
  return __builtin_amdgcn_mfma_f32_16x16x32_bf16(a, b, c, 0, 0, 0);
}

__device__ __forceinline__ f32x16 mfma32(bf16x8 a, bf16x8 b, f32x16 c){
  return __builtin_amdgcn_mfma_f32_32x32x16_bf16(a, b, c, 0, 0, 0);
}

__device__ __forceinline__ unsigned int cvtpk(float lo, float hi){
  unsigned int r;
  asm("v_cvt_pk_bf16_f32 %0, %1, %2" : "=v"(r) : "v"(lo), "v"(hi));
  return r;
}

__device__ __forceinline__ bf16x8 u2b(u32x4 u){
  union { u32x4 a; bf16x8 b; } c; c.a = u; return c.b;
}

// ---------------- W [k][n] fp32 -> Wt [mat][n][k] bf16 ----------------
__global__ void cvt_w(const float* __restrict__ Wq, const float* __restrict__ Wk,
                      const float* __restrict__ Wv, short* __restrict__ Wt){
  int i = blockIdx.x * 256 + threadIdx.x;          // 0 .. 3*768*768-1
  int mat = i / (ND*ND);
  int rem = i - mat * (ND*ND);
  int k = rem / ND;
  int n = rem - k * ND;
  const float* W = (mat == 0) ? Wq : (mat == 1 ? Wk : Wv);
  Wt[(long)mat*ND*ND + (long)n*ND + k] = (short)f2bf(W[rem]);
}

// ---------------- fused QKV GEMM v9d: R19 + wave reshape 4Mx2N (M64xN128 per
// wave). Cuts the expensive fp32-A fragment reads per wave 8->4 (16->8 f4
// ds_reads, 32->16 cvtpk) while B b128 reads go 4->8 and MFMA count stays 32.
// Staging, ring, ledger identical to R19. ----------
__global__ __launch_bounds__(512, 2)
void qkv_gemm(const float* __restrict__ from_t, const float* __restrict__ to_t,
              const short* __restrict__ Wt,
              const float* __restrict__ bq, const float* __restrict__ bk,
              const float* __restrict__ bv,
              short* __restrict__ Qw, short* __restrict__ Kw, short* __restrict__ Vtw){
  __shared__ short smem[73728];   // 144 KB: A slot s @ s*16384 (32KB fp32), B @ 49152 + s*8192

  int bid = blockIdx.x;                       // 1152 blocks, %8==0
  int wg  = (bid & 7) * 144 + (bid >> 3);     // XCD-contiguous chunks of 144
  int mt  = wg / 9;                           // 0..127 (slowest)
  int r2  = wg - mt * 9;
  int nt  = r2 / 3;                           // 0..2
  int mat = r2 - nt * 3;                      // 0..2 (fastest: 3 mats share A-panel in L2)

  const float* Af = (mat == 0) ? from_t : to_t;
  const short* Wp = Wt + (long)mat * ND * ND;

  int t_ = threadIdx.x, wv = t_ >> 6, l = t_ & 63, g = l >> 4, c = l & 15;
  int wm = wv >> 1, wn = wv & 1;              // 4M x 2N waves, 64x128 per wave
  int m0 = mt * 256, n0 = nt * 256;

  // stage one eighth (ci 0..5) of tile kt into ring slot sl.
  // chunks 0..31 = A (fp32, 256 rows x 8 slots of 16B), 32..47 = B (bf16).
  auto stage = [&](int kt, int sl, int ci){
    int chunk = ci * 8 + wv;                  // wave-uniform
    if (chunk < 32){
      int idx = chunk * 64 + l;               // 0..2047
      int row = idx >> 3, slot = idx & 7;
      int x  = slot ^ (row & 7);
      int j  = 2 * (x & 3) + ((x >> 2) ^ ((row >> 3) & 1));   // inverse slot-perm
      const float* gp = Af + (long)(m0 + row) * ND + kt * 32 + j * 4;
      __builtin_amdgcn_global_load_lds((const GAS unsigned int*)gp,
                                       (LAS unsigned int*)(smem + sl * 16384 + idx * 8), 16, 0, 0);
    } else {
      int idx = (chunk - 32) * 64 + l;        // 0..1023
      int row = idx >> 2, slot = idx & 3;
      const short* gp = Wp + (long)(n0 + row) * ND + kt * 32 + ((slot ^ ((row >> 1) & 3)) << 3);
      __builtin_amdgcn_global_load_lds((const GAS unsigned int*)gp,
                                       (LAS unsigned int*)(smem + 49152 + sl * 8192 + idx * 8), 16, 0, 0);
    }
  };

  // read one A fragment (k=8g..8g+7) as fp32 and convert to bf16x8
  auto ldA = [&](const short* Asl, int row) -> bf16x8 {
    const char* base = (const char*)Asl + row * 128;
    int r7 = row & 7, r3 = (row >> 3) & 1;
    f4 lo = *(const f4*)(base + (((g | (r3 << 2)) ^ r7) << 4));        // j = 2g
    f4 hi = *(const f4*)(base + (((g | ((1 ^ r3) << 2)) ^ r7) << 4));  // j = 2g+1
    u32x4 pk;
    pk[0] = cvtpk(lo[0], lo[1]); pk[1] = cvtpk(lo[2], lo[3]);
    pk[2] = cvtpk(hi[0], hi[1]); pk[3] = cvtpk(hi[2], hi[3]);
    return u2b(pk);
  };

  f32x4 zero = {0.f, 0.f, 0.f, 0.f};
  f32x4 acc[4][8];                            // [M-frag][N-frag] (64x128 wave tile)
  #pragma unroll
  for (int i = 0; i < 4; ++i)
    #pragma unroll
    for (int j = 0; j < 8; ++j) acc[i][j] = zero;

  // prologue: tiles 0,1 fully staged (6 glds/thread each; 12 outstanding)
  #pragma unroll
  for (int ci = 0; ci < 6; ++ci) stage(0, 0, ci);
  #pragma unroll
  for (int ci = 0; ci < 6; ++ci) stage(1, 1, ci);

  auto step = [&](int sl, int sl2, int t){
    const short* Asl = smem + sl * 16384;
    const short* Bsl = smem + 49152 + sl * 8192;
    if (t == 23) asm volatile("s_waitcnt vmcnt(0)" ::: "memory");
    else         asm volatile("s_waitcnt vmcnt(6)" ::: "memory");
    __builtin_amdgcn_s_barrier();
    bf16x8 af[4], bfv[8];
    #pragma unroll
    for (int ms = 0; ms < 4; ++ms)
      af[ms] = ldA(Asl, wm * 64 + ms * 16 + c);
    if (t < 22){ stage(t + 2, sl2, 0); stage(t + 2, sl2, 1); }
    #pragma unroll
    for (int ns = 0; ns < 8; ++ns){
      int row = wn * 128 + ns * 16 + c;
      bfv[ns] = *(const bf16x8*)(Bsl + row * 32 + ((g ^ ((row >> 1) & 3)) << 3));
    }
    if (t < 22){ stage(t + 2, sl2, 2); stage(t + 2, sl2, 3); }
    if (t < 22){ stage(t + 2, sl2, 4); stage(t + 2, sl2, 5); }
    __builtin_amdgcn_s_setprio(1);
    #pragma unroll
    for (int ms = 0; ms < 4; ++ms)
      #pragma unroll
      for (int ns = 0; ns < 8; ++ns)
        acc[ms][ns] = mfma16(af[ms], bfv[ns], acc[ms][ns]);
    __builtin_amdgcn_s_setprio(0);
  };

  for (int it = 0; it < 8; ++it){
    int t = it * 3;
    step(0, 2, t);
    step(1, 0, t + 1);
    step(2, 1, t + 2);
  }

  __builtin_amdgcn_s_barrier();              // all K-loop LDS reads done everywhere

  // ---- epilogue: wave owns 64 rows x 128 cols (2 heads); process per 64-col
  // half (h2) through a wave-private 8KB LDS chunk -> coalesced 16B stores
  const float* bias = (mat == 0) ? bq : (mat == 1 ? bk : bv);
  short* chunk = smem + wv * 4096;           // 8 KB per wave (inside A region)
  int mbase = m0 + wm * 64;                  // 64-aligned, never crosses b
  int b = mbase >> 9, s0 = mbase & 511;

  if (mat < 2){
    short* O = (mat == 0) ? Qw : Kw;
    float scl = (mat == 0) ? QSCALE : 1.0f;
    #pragma unroll
    for (int h2 = 0; h2 < 2; ++h2){
      int n0g = n0 + wn * 128 + h2 * 64;     // 64 cols = exactly one head
      int hq = n0g >> 6;
      float bb[4];
      #pragma unroll
      for (int ns = 0; ns < 4; ++ns) bb[ns] = bias[n0g + ns * 16 + c];
      #pragma unroll
      for (int msl = 0; msl < 4; ++msl){
        #pragma unroll
        for (int ns = 0; ns < 4; ++ns){
          int col = ns * 16 + c;             // hs
          #pragma unroll
          for (int i = 0; i < 4; ++i){
            int row = msl * 16 + g * 4 + i;  // s-local 0..63
            chunk[row * 64 + (((col >> 3) ^ (row & 7)) << 3) + (col & 7)] =
                (short)f2bf((acc[msl][h2 * 4 + ns][i] + bb[ns]) * scl);
          }
        }
      }
      asm volatile("s_waitcnt lgkmcnt(0)" ::: "memory");
      __builtin_amdgcn_sched_barrier(0);
      #pragma unroll
      for (int rr = 0; rr < 8; ++rr){
        int row = rr * 8 + (l >> 3);         // 0..63, all 64 rows covered
        int slot = l & 7;
        bf16x8 v = *(const bf16x8*)(chunk + row * 64 + ((slot ^ (row & 7)) << 3));
        *(bf16x8*)(O + (((long)(b * NH + hq) * NS + s0 + row) << 6) + slot * 8) = v;
      }
      if (h2 == 0){ asm volatile("s_waitcnt lgkmcnt(0)" ::: "memory"); }
    }
  } else {
    #pragma unroll
    for (int h2 = 0; h2 < 2; ++h2){
      int n0g = n0 + wn * 128 + h2 * 64;     // 64 hs-cols = exactly one head
      int hq = n0g >> 6;
      float bb[4];
      #pragma unroll
      for (int ns = 0; ns < 4; ++ns) bb[ns] = bias[n0g + ns * 16 + c];
      #pragma unroll
      for (int msl = 0; msl < 4; ++msl){
        #pragma unroll
        for (int ns = 0; ns < 4; ++ns){
          int hs = ns * 16 + c;              // row 0..63
          #pragma unroll
          for (int i = 0; i < 4; ++i){
            int col = msl * 16 + g * 4 + i;  // s-local 0..63
            chunk[hs * 64 + (((col >> 3) ^ (hs & 7)) << 3) + (col & 7)] =
                (short)f2bf(acc[msl][h2 * 4 + ns][i] + bb[ns]);
          }
        }
      }
      asm volatile("s_waitcnt lgkmcnt(0)" ::: "memory");
      __builtin_amdgcn_sched_barrier(0);
      #pragma unroll
      for (int rr = 0; rr < 8; ++rr){
        int hs = rr * 8 + (l >> 3);
        int slot = l & 7;
        bf16x8 v = *(const bf16x8*)(chunk + hs * 64 + ((slot ^ (hs & 7)) << 3));
        *(bf16x8*)(Vtw + (long)((b * NH + hq) * 64 + hs) * NS + s0 + slot * 8) = v;
      }
      if (h2 == 0){ asm volatile("s_waitcnt lgkmcnt(0)" ::: "memory"); }
    }
  }
}

// ---------------- attention v4 (R15, validated): 32x32 MFMA, swapped operands,
// P in registers, T15 att[2] double-pipeline + setprio. ----------
__global__ __launch_bounds__(512, 1)
void attn_kernel(const short* __restrict__ Qw, const short* __restrict__ Kw,
                 const short* __restrict__ Vtw, float* __restrict__ out){
  extern __shared__ char smem[];
  short* Ks = (short*)smem;              // [512][64] bf16, swizzled rows 128B, 64 KB
  short* Vs = (short*)(smem + 65536);    // [64][512] bf16, swizzled rows 1KB, 64 KB

  int bh = blockIdx.x;                   // 768 blocks
  int t = threadIdx.x, wv = t >> 6, l = t & 63;
  int lam = l & 31, hi = l >> 5;
  int r7 = lam & 7;

  const short* Kb = Kw  + (long)bh * NS * NHS;
  const short* Vb = Vtw + (long)bh * NS * NHS;

  // stage K [key][d] and Vt [d][key] once, 128 chunks of 1KB over 8 waves
  #pragma unroll
  for (int it = 0; it < 8; ++it){
    int chunk = it * 8 + wv;             // wave-uniform, 0..63
    {
      int idx = chunk * 64 + l;
      int row = idx >> 3, slot = idx & 7;
      const short* gk = Kb + row * 64 + ((slot ^ (row & 7)) * 8);
      __builtin_amdgcn_global_load_lds((const GAS unsigned int*)gk,
                                       (LAS unsigned int*)(Ks + chunk * 512), 16, 0, 0);
    }
    {
      int row = chunk, slot = l;         // one chunk = one d-row
      const short* gv = Vb + (long)row * NS + (((slot & 56) | ((slot & 7) ^ (row & 7))) * 8);
      __builtin_amdgcn_global_load_lds((const GAS unsigned int*)gv,
                                       (LAS unsigned int*)(Vs + chunk * 512), 16, 0, 0);
    }
  }
  __syncthreads();

  int b = bh / NH, h = bh - b * NH;
  float* outb = out + (long)b * NS * ND + (long)h * 64;

  for (int qt = 0; qt < 2; ++qt){
    int q0 = wv * 64 + qt * 32;
    // Q as B-operand: B[k=hi*8+j][col=q=lam], d = dk*16 + hi*8 + j
    const short* Qb = Qw + (((long)bh * NS + q0 + lam) << 6) + hi * 8;
    bf16x8 qf[4];
    #pragma unroll
    for (int dk = 0; dk < 4; ++dk) qf[dk] = *(const bf16x8*)(Qb + dk * 16);

    f32x16 o0, o1;                       // O[q=q0+lam][d=(reg&3)+8*(reg>>2)+4*hi+32*dh]
    #pragma unroll
    for (int j = 0; j < 16; ++j){ o0[j] = 0.f; o1[j] = 0.f; }
    float m_run = -1e30f, lsum = 0.f;

    // ---- T15 pipeline state: two score tiles + two K-frag sets
    f32x16 s2[2];
    bf16x8 kfr[2][4];
    {
      const char* kb = (const char*)Ks + lam * 128;       // chunk 0
      #pragma unroll
      for (int dk = 0; dk < 4; ++dk)
        kfr[0][dk] = *(const bf16x8*)(kb + (((hi + 2 * dk) ^ r7) << 4));
      #pragma unroll
      for (int j = 0; j < 16; ++j) s2[0][j] = 0.f;
      __builtin_amdgcn_s_setprio(1);
      #pragma unroll
      for (int dk = 0; dk < 4; ++dk) s2[0] = mfma32(kfr[0][dk], qf[dk], s2[0]);
      __builtin_amdgcn_s_setprio(0);
    }

    #pragma unroll
    for (int ch = 0; ch < 16; ++ch){
      const int cur = ch & 1, nxt = cur ^ 1;

      // (1) ds_read next chunk's K-frags (latency hidden under softmax VALU)
      if (ch < 15){
        const char* kb = (const char*)Ks + ((ch + 1) * 32 + lam) * 128;
        #pragma unroll
        for (int dk = 0; dk < 4; ++dk)
          kfr[nxt][dk] = *(const bf16x8*)(kb + (((hi + 2 * dk) ^ r7) << 4));
      }

      // (2) softmax on s2[cur] (defer-max THR=8; deferred 1/sum)
      float t8[8], t4[4];
      #pragma unroll
      for (int j = 0; j < 8; ++j) t8[j] = fmaxf(s2[cur][j], s2[cur][j + 8]);
      #pragma unroll
      for (int j = 0; j < 4; ++j) t4[j] = fmaxf(t8[j], t8[j + 4]);
      float m1 = fmaxf(fmaxf(t4[0], t4[1]), fmaxf(t4[2], t4[3]));
      float pmax = fmaxf(m1, __shfl_xor(m1, 32));
      if (__any(pmax > m_run + 8.0f)){
        float mnew = fmaxf(m_run, pmax);
        float cf = exp2f(m_run - mnew);
        lsum *= cf;
        #pragma unroll
        for (int j = 0; j < 16; ++j){ o0[j] *= cf; o1[j] *= cf; }
        m_run = mnew;
      }
      float p[16];
      #pragma unroll
      for (int j = 0; j < 16; ++j) p[j] = exp2f(s2[cur][j] - m_run);
      float a8[8], a4[4];
      #pragma unroll
      for (int j = 0; j < 8; ++j) a8[j] = p[j] + p[j + 8];
      #pragma unroll
      for (int j = 0; j < 4; ++j) a4[j] = a8[j] + a8[j + 4];
      lsum += (a4[0] + a4[1]) + (a4[2] + a4[3]);

      // (3) issue next chunk's QK^T — MFMA pipe overlaps the pack VALU below
      if (ch < 15){
        #pragma unroll
        for (int j = 0; j < 16; ++j) s2[nxt][j] = 0.f;
        __builtin_amdgcn_s_setprio(1);
        #pragma unroll
        for (int dk = 0; dk < 4; ++dk) s2[nxt] = mfma32(kfr[nxt][dk], qf[dk], s2[nxt]);
        __builtin_amdgcn_s_setprio(0);
      }

      // (4) P -> bf16 fragments, single-partner exchange (lane ^ 32)
      unsigned int w[8];
      #pragma unroll
      for (int rr = 0; rr < 8; ++rr) w[rr] = cvtpk(p[2 * rr], p[2 * rr + 1]);
      unsigned int y0 = (unsigned int)__shfl_xor((int)(hi ? w[0] : w[2]), 32);
      unsigned int y1 = (unsigned int)__shfl_xor((int)(hi ? w[1] : w[3]), 32);
      unsigned int y2 = (unsigned int)__shfl_xor((int)(hi ? w[4] : w[6]), 32);
      unsigned int y3 = (unsigned int)__shfl_xor((int)(hi ? w[5] : w[7]), 32);
      u32x4 fa, fb;
      if (hi){
        fa[0] = y0;   fa[1] = y1;   fa[2] = w[2]; fa[3] = w[3];   // keys 8..15
        fb[0] = y2;   fb[1] = y3;   fb[2] = w[6]; fb[3] = w[7];   // keys 24..31
      } else {
        fa[0] = w[0]; fa[1] = w[1]; fa[2] = y0;   fa[3] = y1;     // keys 0..7
        fb[0] = w[4]; fb[1] = w[5]; fb[2] = y2;   fb[3] = y3;     // keys 16..23
      }
      bf16x8 pa = u2b(fa), pb = u2b(fb);

      // (5) PV (swapped): o[dh] += mfma32(V^T-frag, P-frag)
      const char* vb0 = (const char*)Vs + lam * 1024;          // d = lam
      const char* vb1 = (const char*)Vs + (32 + lam) * 1024;   // d = 32+lam
      int sl0 = ch * 4 + hi, sl1 = ch * 4 + 2 + hi;
      int sw0 = ((sl0 & 56) | ((sl0 & 7) ^ r7)) << 4;
      int sw1 = ((sl1 & 56) | ((sl1 & 7) ^ r7)) << 4;
      bf16x8 v00 = *(const bf16x8*)(vb0 + sw0);
      bf16x8 v01 = *(const bf16x8*)(vb0 + sw1);
      bf16x8 v10 = *(const bf16x8*)(vb1 + sw0);
      bf16x8 v11 = *(const bf16x8*)(vb1 + sw1);
      __builtin_amdgcn_s_setprio(1);
      o0 = mfma32(v00, pa, o0);
      o0 = mfma32(v01, pb, o0);
      o1 = mfma32(v10, pa, o1);
      o1 = mfma32(v11, pb, o1);
      __builtin_amdgcn_s_setprio(0);
    }

    // ---- epilogue: combine l across partner, deferred 1/sum, float4 stores
    float lt = lsum + __shfl_xor(lsum, 32);
    float invl = 1.0f / lt;
    float* orow = outb + (long)(q0 + lam) * ND;
    #pragma unroll
    for (int r = 0; r < 4; ++r){
      f4 u0, u1;
      #pragma unroll
      for (int jj = 0; jj < 4; ++jj){
        u0[jj] = o0[4 * r + jj] * invl;
        u1[jj] = o1[4 * r + jj] * invl;
      }
      *(f4*)(orow + 4 * hi + 8 * r)      = u0;   // d = 4hi+8r+{0..3}
      *(f4*)(orow + 32 + 4 * hi + 8 * r) = u1;   // d = 32+4hi+8r+{0..3}
    }
  }
}

// ---------------- launch ----------------
extern "C" void kernel_launch(void* const* d_in, const int* in_sizes, int n_in,
                              void* d_out, int out_size, void* d_ws, size_t ws_size,
                              hipStream_t stream){
  const float* from_t = (const float*)d_in[0];
  const float* to_t   = (const float*)d_in[1];
  const float* Wq = (const float*)d_in[2];
  const float* bq = (const float*)d_in[3];
  const float* Wk = (const float*)d_in[4];
  const float* bk = (const float*)d_in[5];
  const float* Wv = (const float*)d_in[6];
  const float* bv = (const float*)d_in[7];

  short* Wt  = (short*)d_ws;                 // 1769472 bf16
  short* Qw  = Wt  + 1769472;                // 25165824
  short* Kw  = Qw  + 25165824;               // 25165824
  short* Vtw = Kw  + 25165824;               // 25165824  (total ~147 MB)

  cvt_w<<<6912, 256, 0, stream>>>(Wq, Wk, Wv, Wt);
  qkv_gemm<<<1152, 512, 0, stream>>>(from_t, to_t, Wt, bq, bk, bv, Qw, Kw, Vtw);
  attn_kernel<<<768, 512, 131072, stream>>>(Qw, Kw, Vtw, (float*)d_out);
}

// Round 21
// 297.241 us; speedup vs baseline: 1.9382x; 1.9382x over previous
//
#include <hip/hip_runtime.h>
#include <hip/hip_bf16.h>

#define GAS __attribute__((address_space(1)))
#define LAS __attribute__((address_space(3)))

typedef __attribute__((ext_vector_type(8))) short   bf16x8;
typedef __attribute__((ext_vector_type(4))) float   f32x4;
typedef __attribute__((ext_vector_type(16))) float  f32x16;
typedef __attribute__((ext_vector_type(4))) float   f4;
typedef __attribute__((ext_vector_type(8))) short   s8v;
typedef __attribute__((ext_vector_type(4))) unsigned int u32x4;

#define NB  64
#define NS  512
#define ND  768
#define NH  12
#define NHS 64
#define NM  (NB*NS)    /* 32768 */

// 0.125 * log2(e): folded into Q so softmax uses exp2 directly
#define QSCALE 0.18033688011112042f

__device__ __forceinline__ unsigned short f2bf(float x){
  unsigned int u = __float_as_uint(x);
  u += 0x7fffu + ((u >> 16) & 1u);       // round-to-nearest-even
  return (unsigned short)(u >> 16);
}

__device__ __forceinline__ f32x4 mfma16(bf16x8 a, bf16x8 b, f32x4 c){
  return __builtin_amdgcn_mfma_f32_16x16x32_bf16(a, b, c, 0, 0, 0);
}

__device__ __forceinline__ f32x16 mfma32(bf16x8 a, bf16x8 b, f32x16 c){
  return __builtin_amdgcn_mfma_f32_32x32x16_bf16(a, b, c, 0, 0, 0);
}

__device__ __forceinline__ unsigned int cvtpk(float lo, float hi){
  unsigned int r;
  asm("v_cvt_pk_bf16_f32 %0, %1, %2" : "=v"(r) : "v"(lo), "v"(hi));
  return r;
}

__device__ __forceinline__ bf16x8 u2b(u32x4 u){
  union { u32x4 a; bf16x8 b; } c; c.a = u; return c.b;
}

// ---------------- W [k][n] fp32 -> Wt [mat][n][k] bf16 ----------------
__global__ void cvt_w(const float* __restrict__ Wq, const float* __restrict__ Wk,
                      const float* __restrict__ Wv, short* __restrict__ Wt){
  int i = blockIdx.x * 256 + threadIdx.x;          // 0 .. 3*768*768-1
  int mat = i / (ND*ND);
  int rem = i - mat * (ND*ND);
  int k = rem / ND;
  int n = rem - k * ND;
  const float* W = (mat == 0) ? Wq : (mat == 1 ? Wk : Wv);
  Wt[(long)mat*ND*ND + (long)n*ND + k] = (short)f2bf(W[rem]);
}

// ---------------- fused QKV GEMM (R19, session best): fp32-A in LDS via
// global_load_lds, converted on ds_read; 2Mx4N waves (128x64/wave); triple
// ring; counted vmcnt(6); L2-aware block order (mat fastest). ----------
__global__ __launch_bounds__(512, 2)
void qkv_gemm(const float* __restrict__ from_t, const float* __restrict__ to_t,
              const short* __restrict__ Wt,
              const float* __restrict__ bq, const float* __restrict__ bk,
              const float* __restrict__ bv,
              short* __restrict__ Qw, short* __restrict__ Kw, short* __restrict__ Vtw){
  __shared__ short smem[73728];   // 144 KB: A slot s @ s*16384 (32KB fp32), B @ 49152 + s*8192

  int bid = blockIdx.x;                       // 1152 blocks, %8==0
  int wg  = (bid & 7) * 144 + (bid >> 3);     // XCD-contiguous chunks of 144
  int mt  = wg / 9;                           // 0..127 (slowest)
  int r2  = wg - mt * 9;
  int nt  = r2 / 3;                           // 0..2
  int mat = r2 - nt * 3;                      // 0..2 (fastest: 3 mats share A-panel in L2)

  const float* Af = (mat == 0) ? from_t : to_t;
  const short* Wp = Wt + (long)mat * ND * ND;

  int t_ = threadIdx.x, wv = t_ >> 6, l = t_ & 63, g = l >> 4, c = l & 15;
  int wm = wv >> 2, wn = wv & 3;              // 2M x 4N waves, 128x64 per wave
  int m0 = mt * 256, n0 = nt * 256;

  // stage one eighth (ci 0..5) of tile kt into ring slot sl.
  // chunks 0..31 = A (fp32, 256 rows x 8 slots of 16B), 32..47 = B (bf16).
  auto stage = [&](int kt, int sl, int ci){
    int chunk = ci * 8 + wv;                  // wave-uniform
    if (chunk < 32){
      int idx = chunk * 64 + l;               // 0..2047
      int row = idx >> 3, slot = idx & 7;
      int x  = slot ^ (row & 7);
      int j  = 2 * (x & 3) + ((x >> 2) ^ ((row >> 3) & 1));   // inverse slot-perm
      const float* gp = Af + (long)(m0 + row) * ND + kt * 32 + j * 4;
      __builtin_amdgcn_global_load_lds((const GAS unsigned int*)gp,
                                       (LAS unsigned int*)(smem + sl * 16384 + idx * 8), 16, 0, 0);
    } else {
      int idx = (chunk - 32) * 64 + l;        // 0..1023
      int row = idx >> 2, slot = idx & 3;
      const short* gp = Wp + (long)(n0 + row) * ND + kt * 32 + ((slot ^ ((row >> 1) & 3)) << 3);
      __builtin_amdgcn_global_load_lds((const GAS unsigned int*)gp,
                                       (LAS unsigned int*)(smem + 49152 + sl * 8192 + idx * 8), 16, 0, 0);
    }
  };

  // read one A fragment (k=8g..8g+7) as fp32 and convert to bf16x8
  auto ldA = [&](const short* Asl, int row) -> bf16x8 {
    const char* base = (const char*)Asl + row * 128;
    int r7 = row & 7, r3 = (row >> 3) & 1;
    f4 lo = *(const f4*)(base + (((g | (r3 << 2)) ^ r7) << 4));        // j = 2g
    f4 hi = *(const f4*)(base + (((g | ((1 ^ r3) << 2)) ^ r7) << 4));  // j = 2g+1
    u32x4 pk;
    pk[0] = cvtpk(lo[0], lo[1]); pk[1] = cvtpk(lo[2], lo[3]);
    pk[2] = cvtpk(hi[0], hi[1]); pk[3] = cvtpk(hi[2], hi[3]);
    return u2b(pk);
  };

  f32x4 zero = {0.f, 0.f, 0.f, 0.f};
  f32x4 acc[8][4];
  #pragma unroll
  for (int i = 0; i < 8; ++i)
    #pragma unroll
    for (int j = 0; j < 4; ++j) acc[i][j] = zero;

  // prologue: tiles 0,1 fully staged (6 glds/thread each; 12 outstanding)
  #pragma unroll
  for (int ci = 0; ci < 6; ++ci) stage(0, 0, ci);
  #pragma unroll
  for (int ci = 0; ci < 6; ++ci) stage(1, 1, ci);

  auto step = [&](int sl, int sl2, int t){
    const short* Asl = smem + sl * 16384;
    const short* Bsl = smem + 49152 + sl * 8192;
    if (t == 23) asm volatile("s_waitcnt vmcnt(0)" ::: "memory");
    else         asm volatile("s_waitcnt vmcnt(6)" ::: "memory");
    __builtin_amdgcn_s_barrier();
    bf16x8 af[8], bfv[4];
    #pragma unroll
    for (int ms = 0; ms < 4; ++ms)
      af[ms] = ldA(Asl, wm * 128 + ms * 16 + c);
    if (t < 22){ stage(t + 2, sl2, 0); stage(t + 2, sl2, 1); }
    #pragma unroll
    for (int ns = 0; ns < 4; ++ns){
      int row = wn * 64 + ns * 16 + c;
      bfv[ns] = *(const bf16x8*)(Bsl + row * 32 + ((g ^ ((row >> 1) & 3)) << 3));
    }
    if (t < 22){ stage(t + 2, sl2, 2); stage(t + 2, sl2, 3); }
    #pragma unroll
    for (int ms = 4; ms < 8; ++ms)
      af[ms] = ldA(Asl, wm * 128 + ms * 16 + c);
    if (t < 22){ stage(t + 2, sl2, 4); stage(t + 2, sl2, 5); }
    __builtin_amdgcn_s_setprio(1);
    #pragma unroll
    for (int ms = 0; ms < 8; ++ms)
      #pragma unroll
      for (int ns = 0; ns < 4; ++ns)
        acc[ms][ns] = mfma16(af[ms], bfv[ns], acc[ms][ns]);
    __builtin_amdgcn_s_setprio(0);
  };

  for (int it = 0; it < 8; ++it){
    int t = it * 3;
    step(0, 2, t);
    step(1, 0, t + 1);
    step(2, 1, t + 2);
  }

  __builtin_amdgcn_s_barrier();              // all K-loop LDS reads done everywhere

  // ---- epilogue: wave-private 8KB LDS chunk -> coalesced 16B stores
  int n0g = n0 + wn * 64;                    // 64 cols = exactly one head
  const float* bias = (mat == 0) ? bq : (mat == 1 ? bk : bv);
  float bb[4];
  #pragma unroll
  for (int ns = 0; ns < 4; ++ns) bb[ns] = bias[n0g + ns * 16 + c];
  short* chunk = smem + wv * 4096;           // 8 KB per wave (inside A region)
  int hq = n0g >> 6;

  if (mat < 2){
    short* O = (mat == 0) ? Qw : Kw;
    float scl = (mat == 0) ? QSCALE : 1.0f;
    #pragma unroll
    for (int sp = 0; sp < 2; ++sp){
      #pragma unroll
      for (int msl = 0; msl < 4; ++msl){
        #pragma unroll
        for (int ns = 0; ns < 4; ++ns){
          int col = ns * 16 + c;             // hs
          #pragma unroll
          for (int i = 0; i < 4; ++i){
            int row = msl * 16 + g * 4 + i;  // s-local 0..63
            chunk[row * 64 + (((col >> 3) ^ (row & 7)) << 3) + (col & 7)] =
                (short)f2bf((acc[sp * 4 + msl][ns][i] + bb[ns]) * scl);
          }
        }
      }
      asm volatile("s_waitcnt lgkmcnt(0)" ::: "memory");
      __builtin_amdgcn_sched_barrier(0);
      #pragma unroll
      for (int rr = 0; rr < 8; ++rr){
        int row = rr * 8 + (l >> 3);         // 0..63, all 64 rows covered
        int slot = l & 7;
        bf16x8 v = *(const bf16x8*)(chunk + row * 64 + ((slot ^ (row & 7)) << 3));
        int m = m0 + wm * 128 + sp * 64 + row;
        int b = m >> 9, s2 = m & 511;
        *(bf16x8*)(O + (((long)(b * NH + hq) * NS + s2) << 6) + slot * 8) = v;
      }
      if (sp == 0){ asm volatile("s_waitcnt lgkmcnt(0)" ::: "memory"); }
    }
  } else {
    #pragma unroll
    for (int sp = 0; sp < 2; ++sp){
      #pragma unroll
      for (int msl = 0; msl < 4; ++msl){
        #pragma unroll
        for (int ns = 0; ns < 4; ++ns){
          int hs = ns * 16 + c;              // row 0..63
          #pragma unroll
          for (int i = 0; i < 4; ++i){
            int col = msl * 16 + g * 4 + i;  // s-local 0..63
            chunk[hs * 64 + (((col >> 3) ^ (hs & 7)) << 3) + (col & 7)] =
                (short)f2bf(acc[sp * 4 + msl][ns][i] + bb[ns]);
          }
        }
      }
      asm volatile("s_waitcnt lgkmcnt(0)" ::: "memory");
      __builtin_amdgcn_sched_barrier(0);
      int mbase = m0 + wm * 128 + sp * 64;   // 64-aligned, never crosses b
      int b = mbase >> 9, s0 = mbase & 511;
      #pragma unroll
      for (int rr = 0; rr < 8; ++rr){
        int hs = rr * 8 + (l >> 3);
        int slot = l & 7;
        bf16x8 v = *(const bf16x8*)(chunk + hs * 64 + ((slot ^ (hs & 7)) << 3));
        *(bf16x8*)(Vtw + (long)((b * NH + hq) * 64 + hs) * NS + s0 + slot * 8) = v;
      }
      if (sp == 0){ asm volatile("s_waitcnt lgkmcnt(0)" ::: "memory"); }
    }
  }
}

// ---------------- attention v4 (R15, validated): 32x32 MFMA, swapped operands,
// P in registers, T15 att[2] double-pipeline + setprio. ----------
__global__ __launch_bounds__(512, 1)
void attn_kernel(const short* __restrict__ Qw, const short* __restrict__ Kw,
                 const short* __restrict__ Vtw, float* __restrict__ out){
  extern __shared__ char smem[];
  short* Ks = (short*)smem;              // [512][64] bf16, swizzled rows 128B, 64 KB
  short* Vs = (short*)(smem + 65536);    // [64][512] bf16, swizzled rows 1KB, 64 KB

  int bh = blockIdx.x;                   // 768 blocks
  int t = threadIdx.x, wv = t >> 6, l = t & 63;
  int lam = l & 31, hi = l >> 5;
  int r7 = lam & 7;

  const short* Kb = Kw  + (long)bh * NS * NHS;
  const short* Vb = Vtw + (long)bh * NS * NHS;

  // stage K [key][d] and Vt [d][key] once, 128 chunks of 1KB over 8 waves
  #pragma unroll
  for (int it = 0; it < 8; ++it){
    int chunk = it * 8 + wv;             // wave-uniform, 0..63
    {
      int idx = chunk * 64 + l;
      int row = idx >> 3, slot = idx & 7;
      const short* gk = Kb + row * 64 + ((slot ^ (row & 7)) * 8);
      __builtin_amdgcn_global_load_lds((const GAS unsigned int*)gk,
                                       (LAS unsigned int*)(Ks + chunk * 512), 16, 0, 0);
    }
    {
      int row = chunk, slot = l;         // one chunk = one d-row
      const short* gv = Vb + (long)row * NS + (((slot & 56) | ((slot & 7) ^ (row & 7))) * 8);
      __builtin_amdgcn_global_load_lds((const GAS unsigned int*)gv,
                                       (LAS unsigned int*)(Vs + chunk * 512), 16, 0, 0);
    }
  }
  __syncthreads();

  int b = bh / NH, h = bh - b * NH;
  float* outb = out + (long)b * NS * ND + (long)h * 64;

  for (int qt = 0; qt < 2; ++qt){
    int q0 = wv * 64 + qt * 32;
    // Q as B-operand: B[k=hi*8+j][col=q=lam], d = dk*16 + hi*8 + j
    const short* Qb = Qw + (((long)bh * NS + q0 + lam) << 6) + hi * 8;
    bf16x8 qf[4];
    #pragma unroll
    for (int dk = 0; dk < 4; ++dk) qf[dk] = *(const bf16x8*)(Qb + dk * 16);

    f32x16 o0, o1;                       // O[q=q0+lam][d=(reg&3)+8*(reg>>2)+4*hi+32*dh]
    #pragma unroll
    for (int j = 0; j < 16; ++j){ o0[j] = 0.f; o1[j] = 0.f; }
    float m_run = -1e30f, lsum = 0.f;

    // ---- T15 pipeline state: two score tiles + two K-frag sets
    f32x16 s2[2];
    bf16x8 kfr[2][4];
    {
      const char* kb = (const char*)Ks + lam * 128;       // chunk 0
      #pragma unroll
      for (int dk = 0; dk < 4; ++dk)
        kfr[0][dk] = *(const bf16x8*)(kb + (((hi + 2 * dk) ^ r7) << 4));
      #pragma unroll
      for (int j = 0; j < 16; ++j) s2[0][j] = 0.f;
      __builtin_amdgcn_s_setprio(1);
      #pragma unroll
      for (int dk = 0; dk < 4; ++dk) s2[0] = mfma32(kfr[0][dk], qf[dk], s2[0]);
      __builtin_amdgcn_s_setprio(0);
    }

    #pragma unroll
    for (int ch = 0; ch < 16; ++ch){
      const int cur = ch & 1, nxt = cur ^ 1;

      // (1) ds_read next chunk's K-frags (latency hidden under softmax VALU)
      if (ch < 15){
        const char* kb = (const char*)Ks + ((ch + 1) * 32 + lam) * 128;
        #pragma unroll
        for (int dk = 0; dk < 4; ++dk)
          kfr[nxt][dk] = *(const bf16x8*)(kb + (((hi + 2 * dk) ^ r7) << 4));
      }

      // (2) softmax on s2[cur] (defer-max THR=8; deferred 1/sum)
      float t8[8], t4[4];
      #pragma unroll
      for (int j = 0; j < 8; ++j) t8[j] = fmaxf(s2[cur][j], s2[cur][j + 8]);
      #pragma unroll
      for (int j = 0; j < 4; ++j) t4[j] = fmaxf(t8[j], t8[j + 4]);
      float m1 = fmaxf(fmaxf(t4[0], t4[1]), fmaxf(t4[2], t4[3]));
      float pmax = fmaxf(m1, __shfl_xor(m1, 32));
      if (__any(pmax > m_run + 8.0f)){
        float mnew = fmaxf(m_run, pmax);
        float cf = exp2f(m_run - mnew);
        lsum *= cf;
        #pragma unroll
        for (int j = 0; j < 16; ++j){ o0[j] *= cf; o1[j] *= cf; }
        m_run = mnew;
      }
      float p[16];
      #pragma unroll
      for (int j = 0; j < 16; ++j) p[j] = exp2f(s2[cur][j] - m_run);
      float a8[8], a4[4];
      #pragma unroll
      for (int j = 0; j < 8; ++j) a8[j] = p[j] + p[j + 8];
      #pragma unroll
      for (int j = 0; j < 4; ++j) a4[j] = a8[j] + a8[j + 4];
      lsum += (a4[0] + a4[1]) + (a4[2] + a4[3]);

      // (3) issue next chunk's QK^T — MFMA pipe overlaps the pack VALU below
      if (ch < 15){
        #pragma unroll
        for (int j = 0; j < 16; ++j) s2[nxt][j] = 0.f;
        __builtin_amdgcn_s_setprio(1);
        #pragma unroll
        for (int dk = 0; dk < 4; ++dk) s2[nxt] = mfma32(kfr[nxt][dk], qf[dk], s2[nxt]);
        __builtin_amdgcn_s_setprio(0);
      }

      // (4) P -> bf16 fragments, single-partner exchange (lane ^ 32)
      unsigned int w[8];
      #pragma unroll
      for (int rr = 0; rr < 8; ++rr) w[rr] = cvtpk(p[2 * rr], p[2 * rr + 1]);
      unsigned int y0 = (unsigned int)__shfl_xor((int)(hi ? w[0] : w[2]), 32);
      unsigned int y1 = (unsigned int)__shfl_xor((int)(hi ? w[1] : w[3]), 32);
      unsigned int y2 = (unsigned int)__shfl_xor((int)(hi ? w[4] : w[6]), 32);
      unsigned int y3 = (unsigned int)__shfl_xor((int)(hi ? w[5] : w[7]), 32);
      u32x4 fa, fb;
      if (hi){
        fa[0] = y0;   fa[1] = y1;   fa[2] = w[2]; fa[3] = w[3];   // keys 8..15
        fb[0] = y2;   fb[1] = y3;   fb[2] = w[6]; fb[3] = w[7];   // keys 24..31
      } else {
        fa[0] = w[0]; fa[1] = w[1]; fa[2] = y0;   fa[3] = y1;     // keys 0..7
        fb[0] = w[4]; fb[1] = w[5]; fb[2] = y2;   fb[3] = y3;     // keys 16..23
      }
      bf16x8 pa = u2b(fa), pb = u2b(fb);

      // (5) PV (swapped): o[dh] += mfma32(V^T-frag, P-frag)
      const char* vb0 = (const char*)Vs + lam * 1024;          // d = lam
      const char* vb1 = (const char*)Vs + (32 + lam) * 1024;   // d = 32+lam
      int sl0 = ch * 4 + hi, sl1 = ch * 4 + 2 + hi;
      int sw0 = ((sl0 & 56) | ((sl0 & 7) ^ r7)) << 4;
      int sw1 = ((sl1 & 56) | ((sl1 & 7) ^ r7)) << 4;
      bf16x8 v00 = *(const bf16x8*)(vb0 + sw0);
      bf16x8 v01 = *(const bf16x8*)(vb0 + sw1);
      bf16x8 v10 = *(const bf16x8*)(vb1 + sw0);
      bf16x8 v11 = *(const bf16x8*)(vb1 + sw1);
      __builtin_amdgcn_s_setprio(1);
      o0 = mfma32(v00, pa, o0);
      o0 = mfma32(v01, pb, o0);
      o1 = mfma32(v10, pa, o1);
      o1 = mfma32(v11, pb, o1);
      __builtin_amdgcn_s_setprio(0);
    }

    // ---- epilogue: combine l across partner, deferred 1/sum, float4 stores
    float lt = lsum + __shfl_xor(lsum, 32);
    float invl = 1.0f / lt;
    float* orow = outb + (long)(q0 + lam) * ND;
    #pragma unroll
    for (int r = 0; r < 4; ++r){
      f4 u0, u1;
      #pragma unroll
      for (int jj = 0; jj < 4; ++jj){
        u0[jj] = o0[4 * r + jj] * invl;
        u1[jj] = o1[4 * r + jj] * invl;
      }
      *(f4*)(orow + 4 * hi + 8 * r)      = u0;   // d = 4hi+8r+{0..3}
      *(f4*)(orow + 32 + 4 * hi + 8 * r) = u1;   // d = 32+4hi+8r+{0..3}
    }
  }
}

// ---------------- launch ----------------
extern "C" void kernel_launch(void* const* d_in, const int* in_sizes, int n_in,
                              void* d_out, int out_size, void* d_ws, size_t ws_size,
                              hipStream_t stream){
  const float* from_t = (const float*)d_in[0];
  const float* to_t   = (const float*)d_in[1];
  const float* Wq = (const float*)d_in[2];
  const float* bq = (const float*)d_in[3];
  const float* Wk = (const float*)d_in[4];
  const float* bk = (const float*)d_in[5];
  const float* Wv = (const float*)d_in[6];
  const float* bv = (const float*)d_in[7];

  short* Wt  = (short*)d_ws;                 // 1769472 bf16
  short* Qw  = Wt  + 1769472;                // 25165824
  short* Kw  = Qw  + 25165824;               // 25165824
  short* Vtw = Kw  + 25165824;               // 25165824  (total ~147 MB)

  cvt_w<<<6912, 256, 0, stream>>>(Wq, Wk, Wv, Wt);
  qkv_gemm<<<1152, 512, 0, stream>>>(from_t, to_t, Wt, bq, bk, bv, Qw, Kw, Vtw);
  attn_kernel<<<768, 512, 131072, stream>>>(Qw, Kw, Vtw, (float*)d_out);
}